// Round 8
// baseline (114.032 us; speedup 1.0000x reference)
//
#include <hip/hip_runtime.h>
#include <cfloat>

#define K_CODES 256
#define D_DIM 5
#define T_DIM 16384
#define B_DIM 32
#define NPTS (B_DIM * T_DIM)     // 524288 points
#define NELEM (NPTS * D_DIM)     // 2621440 elements
#define PPT 8                    // consecutive points (t) per thread
#define BLK 128
#define NBLOCKS (NPTS / (PPT * BLK))  // 512 blocks, 2/CU, 4 waves/CU

__global__ __launch_bounds__(BLK) void vq_main(const float* __restrict__ x,
                                               const float* __restrict__ e,
                                               float* __restrict__ out,
                                               double* __restrict__ partials) {
    // ---- per-block codebook prep into LDS (np-exact esq) ----
    // Split tables: 24 B unique per k -> b128 + b64 reads in the hot loop.
    __shared__ float4 cbA[K_CODES];   // c0..c3
    __shared__ float2 cbB[K_CODES];   // c4, esq
    for (int k = threadIdx.x; k < K_CODES; k += BLK) {
        float v0 = e[0 * K_CODES + k];
        float v1 = e[1 * K_CODES + k];
        float v2 = e[2 * K_CODES + k];
        float v3 = e[3 * K_CODES + k];
        float v4 = e[4 * K_CODES + k];
        // np: e**2 rounds each square, then sequential ascending adds (no fma)
        float esq = __fmul_rn(v0, v0);
        esq = __fadd_rn(esq, __fmul_rn(v1, v1));
        esq = __fadd_rn(esq, __fmul_rn(v2, v2));
        esq = __fadd_rn(esq, __fmul_rn(v3, v3));
        esq = __fadd_rn(esq, __fmul_rn(v4, v4));
        cbA[k] = make_float4(v0, v1, v2, v3);
        cbB[k] = make_float2(v4, esq);
    }
    __syncthreads();

    // ---- load this thread's 8 points (2x float4 per d, coalesced) ----
    const int g = blockIdx.x * BLK + threadIdx.x;
    const int p0 = g * PPT;
    const int b = p0 >> 14;            // p0 / T_DIM
    const int t = p0 & (T_DIM - 1);    // p0 % T_DIM (multiple of 8)
    const float* xp = x + (b * D_DIM) * T_DIM + t;

    float xv[PPT][D_DIM];
    float xsq[PPT];
    float best[PPT];
    int bidx[PPT];

    #pragma unroll
    for (int d = 0; d < D_DIM; d++) {
        float4 va = *(const float4*)(xp + d * T_DIM);
        float4 vb = *(const float4*)(xp + d * T_DIM + 4);
        xv[0][d] = va.x; xv[1][d] = va.y; xv[2][d] = va.z; xv[3][d] = va.w;
        xv[4][d] = vb.x; xv[5][d] = vb.y; xv[6][d] = vb.z; xv[7][d] = vb.w;
    }
    // np: x**2 rounds each square, then sequential ascending adds (no fma)
    #pragma unroll
    for (int i = 0; i < PPT; i++) {
        float s = __fmul_rn(xv[i][0], xv[i][0]);
        s = __fadd_rn(s, __fmul_rn(xv[i][1], xv[i][1]));
        s = __fadd_rn(s, __fmul_rn(xv[i][2], xv[i][2]));
        s = __fadd_rn(s, __fmul_rn(xv[i][3], xv[i][3]));
        s = __fadd_rn(s, __fmul_rn(xv[i][4], xv[i][4]));
        xsq[i] = s;
        best[i] = FLT_MAX;
        bidx[i] = 0;
    }

    // ---- scan: sgemm-semantics dot (single-acc ascending FMA chain), numpy's
    // left-to-right (xsq - 2*dot) + esq, strict < ascending k (first-min).
    // Uniform LDS address -> broadcast, conflict-free.
    #pragma unroll 4
    for (int k = 0; k < K_CODES; k++) {
        float4 cA = cbA[k];
        float2 cB = cbB[k];
        #pragma unroll
        for (int i = 0; i < PPT; i++) {
            float dot = __fmul_rn(xv[i][0], cA.x);
            dot = __fmaf_rn(xv[i][1], cA.y, dot);
            dot = __fmaf_rn(xv[i][2], cA.z, dot);
            dot = __fmaf_rn(xv[i][3], cA.w, dot);
            dot = __fmaf_rn(xv[i][4], cB.x, dot);
            float dist = __fadd_rn(__fsub_rn(xsq[i], __fadd_rn(dot, dot)), cB.y);
            if (dist < best[i]) { best[i] = dist; bidx[i] = k; }
        }
    }

    // ---- gather selected codewords, coalesced float4 stores; local loss ----
    float qr[PPT][D_DIM];
    float ls = 0.f;
    #pragma unroll
    for (int i = 0; i < PPT; i++) {
        float4 cA = cbA[bidx[i]];
        float2 cB = cbB[bidx[i]];
        qr[i][0] = cA.x; qr[i][1] = cA.y; qr[i][2] = cA.z;
        qr[i][3] = cA.w; qr[i][4] = cB.x;
        #pragma unroll
        for (int d = 0; d < D_DIM; d++) {
            float df = xv[i][d] - qr[i][d];
            ls += df * df;
        }
    }
    float* op = out + (b * D_DIM) * T_DIM + t;
    #pragma unroll
    for (int d = 0; d < D_DIM; d++) {
        float4 oa, ob;
        oa.x = qr[0][d]; oa.y = qr[1][d]; oa.z = qr[2][d]; oa.w = qr[3][d];
        ob.x = qr[4][d]; ob.y = qr[5][d]; ob.z = qr[6][d]; ob.w = qr[7][d];
        *(float4*)(op + d * T_DIM) = oa;      // straight-through output == q
        *(float4*)(op + d * T_DIM + 4) = ob;
    }

    // ---- block loss reduction -> one slot per block (no atomics/init) ----
    #pragma unroll
    for (int off = 32; off > 0; off >>= 1) ls += __shfl_down(ls, off, 64);
    __shared__ float wsum[BLK / 64];
    int lane = threadIdx.x & 63;
    int wid = threadIdx.x >> 6;
    if (lane == 0) wsum[wid] = ls;
    __syncthreads();
    if (threadIdx.x == 0) {
        float tot = 0.f;
        #pragma unroll
        for (int w = 0; w < BLK / 64; w++) tot += wsum[w];
        partials[blockIdx.x] = (double)tot;  // slot overwritten every launch
    }
}

__global__ __launch_bounds__(NBLOCKS) void vq_finalize(
        const double* __restrict__ partials, float* __restrict__ out) {
    double v = partials[threadIdx.x];   // 512 threads, one slot each
    #pragma unroll
    for (int off = 32; off > 0; off >>= 1) v += __shfl_down(v, off, 64);
    __shared__ double wsum[NBLOCKS / 64];
    int lane = threadIdx.x & 63;
    int wid = threadIdx.x >> 6;
    if (lane == 0) wsum[wid] = v;
    __syncthreads();
    if (threadIdx.x == 0) {
        double tot = 0.0;
        #pragma unroll
        for (int w = 0; w < NBLOCKS / 64; w++) tot += wsum[w];
        float loss = (float)(tot / (double)NELEM);
        out[NELEM] = loss;      // dictionary_loss
        out[NELEM + 1] = loss;  // commitment_loss (identical forward value)
    }
}

extern "C" void kernel_launch(void* const* d_in, const int* in_sizes, int n_in,
                              void* d_out, int out_size, void* d_ws, size_t ws_size,
                              hipStream_t stream) {
    const float* x = (const float*)d_in[0];   // fp32 (B,D,T)
    const float* e = (const float*)d_in[1];   // fp32 (D,K)
    float* out = (float*)d_out;               // fp32: quantized + 2 losses
    double* partials = (double*)d_ws;         // 512 × 8 B

    vq_main<<<NBLOCKS, BLK, 0, stream>>>(x, e, out, partials);
    vq_finalize<<<1, NBLOCKS, 0, stream>>>(partials, out);
}

// Round 9
// 98.690 us; speedup vs baseline: 1.1555x; 1.1555x over previous
//
#include <hip/hip_runtime.h>
#include <cfloat>

#define K_CODES 256
#define D_DIM 5
#define T_DIM 16384
#define B_DIM 32
#define NPTS (B_DIM * T_DIM)     // 524288 points
#define NELEM (NPTS * D_DIM)     // 2621440 elements
#define PPT 4                    // consecutive points (t) per thread (R7-proven)
#define BLK 256
#define NBLOCKS (NPTS / (PPT * BLK))  // 512

typedef float f2 __attribute__((ext_vector_type(2)));  // -> v_pk_*_f32

__global__ __launch_bounds__(BLK) void vq_main(const float* __restrict__ x,
                                               const float* __restrict__ e,
                                               float* __restrict__ out,
                                               double* __restrict__ partials) {
    // ---- per-block codebook prep into LDS (np-exact esq) ----
    __shared__ float4 cbA[K_CODES];                 // c0..c3 (stride 16 B)
    __shared__ __align__(16) float2 cbB[K_CODES];   // c4, esq (stride 8 B)
    {
        int k = threadIdx.x;  // BLK == K_CODES
        float v0 = e[0 * K_CODES + k];
        float v1 = e[1 * K_CODES + k];
        float v2 = e[2 * K_CODES + k];
        float v3 = e[3 * K_CODES + k];
        float v4 = e[4 * K_CODES + k];
        // np: e**2 rounds each square, then sequential ascending adds (no fma)
        float esq = __fmul_rn(v0, v0);
        esq = __fadd_rn(esq, __fmul_rn(v1, v1));
        esq = __fadd_rn(esq, __fmul_rn(v2, v2));
        esq = __fadd_rn(esq, __fmul_rn(v3, v3));
        esq = __fadd_rn(esq, __fmul_rn(v4, v4));
        cbA[k] = make_float4(v0, v1, v2, v3);
        cbB[k] = make_float2(v4, esq);
    }
    __syncthreads();

    // ---- load this thread's 4 points (coalesced float4 per d) ----
    const int g = blockIdx.x * BLK + threadIdx.x;
    const int p0 = g * PPT;
    const int b = p0 >> 14;            // p0 / T_DIM
    const int t = p0 & (T_DIM - 1);    // p0 % T_DIM (multiple of 4)
    const float* xp = x + (b * D_DIM) * T_DIM + t;

    // point-pairs: pair 0 = (pt0,pt1), pair 1 = (pt2,pt3)
    f2 xv[2][D_DIM];
    f2 xsq2[2];
    float best[PPT];
    int bidx[PPT];

    #pragma unroll
    for (int d = 0; d < D_DIM; d++) {
        float4 v = *(const float4*)(xp + d * T_DIM);
        xv[0][d] = (f2){v.x, v.y};
        xv[1][d] = (f2){v.z, v.w};
    }
    // np: x**2 rounds each square, then sequential ascending adds (no fma).
    // Packed mul/add are IEEE-RN per half == __fmul_rn/__fadd_rn per element.
    #pragma unroll
    for (int j = 0; j < 2; j++) {
        f2 s = xv[j][0] * xv[j][0];
        s = s + xv[j][1] * xv[j][1];
        s = s + xv[j][2] * xv[j][2];
        s = s + xv[j][3] * xv[j][3];
        s = s + xv[j][4] * xv[j][4];
        xsq2[j] = s;
    }
    #pragma unroll
    for (int i = 0; i < PPT; i++) { best[i] = FLT_MAX; bidx[i] = 0; }

    // ---- scan, k stepped by 2 so one b128 covers cbB[k],cbB[k+1] ----
    // Per element: dot = rnd-mul then 4 RN-fma (sgemm chain); dist =
    // (xsq - (dot+dot)) + esq left-to-right — numpy-exact. strict < ascending
    // k = np first-min tie-break. Uniform LDS address -> broadcast, no conflict.
    #pragma unroll 2
    for (int k = 0; k < K_CODES; k += 2) {
        float4 cA0 = cbA[k];
        float4 cA1 = cbA[k + 1];
        float4 cBp = *(const float4*)&cbB[k];   // (c4_k, esq_k, c4_k1, esq_k1)
        #pragma unroll
        for (int kk = 0; kk < 2; kk++) {
            float4 cA = kk ? cA1 : cA0;
            f2 c0 = {cA.x, cA.x}, c1 = {cA.y, cA.y}, c2 = {cA.z, cA.z},
               c3 = {cA.w, cA.w};
            f2 c4 = kk ? (f2){cBp.z, cBp.z} : (f2){cBp.x, cBp.x};
            f2 es = kk ? (f2){cBp.w, cBp.w} : (f2){cBp.y, cBp.y};
            #pragma unroll
            for (int j = 0; j < 2; j++) {
                f2 dot = xv[j][0] * c0;                       // v_pk_mul_f32
                dot = __builtin_elementwise_fma(xv[j][1], c1, dot);  // v_pk_fma
                dot = __builtin_elementwise_fma(xv[j][2], c2, dot);
                dot = __builtin_elementwise_fma(xv[j][3], c3, dot);
                dot = __builtin_elementwise_fma(xv[j][4], c4, dot);
                f2 dist = (xsq2[j] - (dot + dot)) + es;       // pk add/sub/add
                int ki = k + kk;
                if (dist.x < best[2 * j]) { best[2 * j] = dist.x; bidx[2 * j] = ki; }
                if (dist.y < best[2 * j + 1]) { best[2 * j + 1] = dist.y; bidx[2 * j + 1] = ki; }
            }
        }
    }

    // ---- gather selected codewords, coalesced float4 stores; local loss ----
    float qr[PPT][D_DIM];
    float ls = 0.f;
    #pragma unroll
    for (int i = 0; i < PPT; i++) {
        float4 cA = cbA[bidx[i]];
        float2 cB = cbB[bidx[i]];
        qr[i][0] = cA.x; qr[i][1] = cA.y; qr[i][2] = cA.z;
        qr[i][3] = cA.w; qr[i][4] = cB.x;
        #pragma unroll
        for (int d = 0; d < D_DIM; d++) {
            float xs = (i & 1) ? xv[i >> 1][d].y : xv[i >> 1][d].x;
            float df = xs - qr[i][d];
            ls += df * df;
        }
    }
    float* op = out + (b * D_DIM) * T_DIM + t;
    #pragma unroll
    for (int d = 0; d < D_DIM; d++) {
        float4 o;
        o.x = qr[0][d]; o.y = qr[1][d]; o.z = qr[2][d]; o.w = qr[3][d];
        *(float4*)(op + d * T_DIM) = o;   // straight-through output == q
    }

    // ---- block loss reduction -> one slot per block (no atomics/init) ----
    #pragma unroll
    for (int off = 32; off > 0; off >>= 1) ls += __shfl_down(ls, off, 64);
    __shared__ float wsum[BLK / 64];
    int lane = threadIdx.x & 63;
    int wid = threadIdx.x >> 6;
    if (lane == 0) wsum[wid] = ls;
    __syncthreads();
    if (threadIdx.x == 0) {
        float tot = 0.f;
        #pragma unroll
        for (int w = 0; w < BLK / 64; w++) tot += wsum[w];
        partials[blockIdx.x] = (double)tot;  // slot overwritten every launch
    }
}

__global__ __launch_bounds__(NBLOCKS) void vq_finalize(
        const double* __restrict__ partials, float* __restrict__ out) {
    double v = partials[threadIdx.x];   // 512 threads, one slot each
    #pragma unroll
    for (int off = 32; off > 0; off >>= 1) v += __shfl_down(v, off, 64);
    __shared__ double wsum[NBLOCKS / 64];
    int lane = threadIdx.x & 63;
    int wid = threadIdx.x >> 6;
    if (lane == 0) wsum[wid] = v;
    __syncthreads();
    if (threadIdx.x == 0) {
        double tot = 0.0;
        #pragma unroll
        for (int w = 0; w < NBLOCKS / 64; w++) tot += wsum[w];
        float loss = (float)(tot / (double)NELEM);
        out[NELEM] = loss;      // dictionary_loss
        out[NELEM + 1] = loss;  // commitment_loss (identical forward value)
    }
}

extern "C" void kernel_launch(void* const* d_in, const int* in_sizes, int n_in,
                              void* d_out, int out_size, void* d_ws, size_t ws_size,
                              hipStream_t stream) {
    const float* x = (const float*)d_in[0];   // fp32 (B,D,T)
    const float* e = (const float*)d_in[1];   // fp32 (D,K)
    float* out = (float*)d_out;               // fp32: quantized + 2 losses
    double* partials = (double*)d_ws;         // 512 × 8 B

    vq_main<<<NBLOCKS, BLK, 0, stream>>>(x, e, out, partials);
    vq_finalize<<<1, NBLOCKS, 0, stream>>>(partials, out);
}